// Round 1
// baseline (225.415 us; speedup 1.0000x reference)
//
#include <hip/hip_runtime.h>
#include <hip/hip_bf16.h>
#include <stdint.h>

#define SEQ   1024
#define NHEAD 12
#define HD    64
#define CDIM  768
#define MTOK  8192
#define NQKV  2304
#define NPAIR 96   // BS*NHEAD

typedef uint16_t u16;
typedef __attribute__((ext_vector_type(8))) __bf16 bf16x8;
typedef __attribute__((ext_vector_type(4))) float  f32x4;

__device__ __forceinline__ u16 f32_to_bf16(float f) {
  union { float f; uint32_t u; } cv; cv.f = f;
  uint32_t u = cv.u;
  return (u16)((u + 0x7FFFu + ((u >> 16) & 1u)) >> 16);
}

__device__ __forceinline__ void load_lds16(const u16* g, u16* l) {
  __builtin_amdgcn_global_load_lds(
      (const __attribute__((address_space(1))) uint32_t*)g,
      (__attribute__((address_space(3))) uint32_t*)l, 16, 0, 0);
}

// ---- convert x (fp32) -> bf16, 8 elems/thread ----
__global__ __launch_bounds__(256) void cvt_x_kernel(const float* __restrict__ in,
                                                    u16* __restrict__ out) {
  int i = blockIdx.x * 256 + threadIdx.x;
  const float4* p = (const float4*)in + (size_t)i * 2;
  float4 a = p[0], b = p[1];
  u16 r[8];
  r[0]=f32_to_bf16(a.x); r[1]=f32_to_bf16(a.y); r[2]=f32_to_bf16(a.z); r[3]=f32_to_bf16(a.w);
  r[4]=f32_to_bf16(b.x); r[5]=f32_to_bf16(b.y); r[6]=f32_to_bf16(b.z); r[7]=f32_to_bf16(b.w);
  uint4 o;
  o.x = (uint32_t)r[0] | ((uint32_t)r[1] << 16);
  o.y = (uint32_t)r[2] | ((uint32_t)r[3] << 16);
  o.z = (uint32_t)r[4] | ((uint32_t)r[5] << 16);
  o.w = (uint32_t)r[6] | ((uint32_t)r[7] << 16);
  ((uint4*)out)[i] = o;
}

// ---- transpose+convert W [K][N] fp32 -> Wt [N][K] bf16 (output-coalesced) ----
__global__ __launch_bounds__(256) void transpose_cvt_kernel(const float* __restrict__ in,
                                                            u16* __restrict__ out,
                                                            int K, int N) {
  int idx = blockIdx.x * 256 + threadIdx.x;
  if (idx >= K * N) return;
  int n = idx / K, k = idx - n * K;
  out[idx] = f32_to_bf16(in[(size_t)k * N + n]);
}

// ---- tiled bf16 GEMM, A[M][K] @ Bt[N][K]^T, 128x128 tile, BK=64, 4 waves ----
// EPI 0: scatter into q/k/v bf16 buffers [pair][n][d]
// EPI 1: plain fp32 store to Cf [M][N]
template<int EPI>
__global__ __launch_bounds__(256) void gemm_bt(const u16* __restrict__ A,
                                               const u16* __restrict__ Bt,
                                               float* __restrict__ Cf,
                                               u16* __restrict__ qb,
                                               u16* __restrict__ kb,
                                               u16* __restrict__ vb,
                                               int M, int N, int K) {
  __shared__ u16 As[128 * 64];
  __shared__ u16 Bs[128 * 64];
  const int ntn = N >> 7;
  int tm = blockIdx.x / ntn, tn = blockIdx.x - tm * ntn;
  int mBase = tm << 7, nBase = tn << 7;
  int tid = threadIdx.x;
  int lane = tid & 63, wid = tid >> 6;
  int wr = (wid >> 1) << 6, wc = (wid & 1) << 6;
  int lr = lane & 15, lk = lane >> 4;

  f32x4 acc[4][4] = {};
  const int nk = K >> 6;
  for (int kt = 0; kt < nk; ++kt) {
    #pragma unroll
    for (int i = 0; i < 4; ++i) {
      int f = i * 2048 + tid * 8;
      int row = f >> 6, col = f & 63;
      load_lds16(A  + (size_t)(mBase + row) * K + kt * 64 + col, &As[f]);
      load_lds16(Bt + (size_t)(nBase + row) * K + kt * 64 + col, &Bs[f]);
    }
    __syncthreads();
    #pragma unroll
    for (int kk = 0; kk < 2; ++kk) {
      bf16x8 af[4], bfr[4];
      #pragma unroll
      for (int i = 0; i < 4; ++i)
        af[i]  = *(const bf16x8*)&As[(wr + i * 16 + lr) * 64 + kk * 32 + lk * 8];
      #pragma unroll
      for (int i = 0; i < 4; ++i)
        bfr[i] = *(const bf16x8*)&Bs[(wc + i * 16 + lr) * 64 + kk * 32 + lk * 8];
      #pragma unroll
      for (int mi = 0; mi < 4; ++mi)
        #pragma unroll
        for (int ni = 0; ni < 4; ++ni)
          acc[mi][ni] = __builtin_amdgcn_mfma_f32_16x16x32_bf16(af[mi], bfr[ni], acc[mi][ni], 0, 0, 0);
    }
    __syncthreads();
  }

  #pragma unroll
  for (int mi = 0; mi < 4; ++mi)
    #pragma unroll
    for (int ni = 0; ni < 4; ++ni)
      #pragma unroll
      for (int j = 0; j < 4; ++j) {
        int m = mBase + wr + mi * 16 + lk * 4 + j;
        int c = nBase + wc + ni * 16 + lr;
        float val = acc[mi][ni][j];
        if (EPI == 0) {
          int s = c / CDIM, rem = c - s * CDIM;
          int h = rem >> 6, d = rem & 63;
          int bb = m >> 10, nn = m & 1023;
          u16* dst = (s == 0) ? qb : ((s == 1) ? kb : vb);
          dst[(((size_t)(bb * NHEAD + h)) << 16) + (nn << 6) + d] = f32_to_bf16(val);
        } else {
          Cf[(size_t)m * N + c] = val;
        }
      }
}

// ---- flash attention: block = (pair, qtile of 64 rows), 4 waves x 16 q-rows ----
__global__ __launch_bounds__(256) void attn_kernel(const u16* __restrict__ q,
                                                   const u16* __restrict__ k,
                                                   const u16* __restrict__ v,
                                                   u16* __restrict__ out) {
  __shared__ u16 Qs[64 * 64];
  __shared__ u16 Ks[64 * 64];
  __shared__ u16 Vt[64 * 64];      // transposed + XOR-swizzled (granules of 8 along k)
  __shared__ u16 Ps[4][16 * 64];   // per-wave P tile

  int pair = blockIdx.x >> 4;
  int qt   = blockIdx.x & 15;
  int b = pair / NHEAD, h = pair - b * NHEAD;
  const u16* Qg = q + ((size_t)pair << 16);
  const u16* Kg = k + ((size_t)pair << 16);
  const u16* Vg = v + ((size_t)pair << 16);
  int tid = threadIdx.x, lane = tid & 63, wid = tid >> 6;
  int lr = lane & 15, lk = lane >> 4;

  // stage Q tile (rows qt*64..+64)
  #pragma unroll
  for (int i = 0; i < 2; ++i) {
    int f = i * 2048 + tid * 8;
    load_lds16(Qg + (qt << 12) + f, &Qs[f]);
  }

  float m_[4], l_[4];
  #pragma unroll
  for (int j = 0; j < 4; ++j) { m_[j] = -1e30f; l_[j] = 0.f; }
  f32x4 acc_o[4] = {};

  for (int kc = 0; kc < 16; ++kc) {
    // stage K chunk (linear)
    #pragma unroll
    for (int i = 0; i < 2; ++i) {
      int f = i * 2048 + tid * 8;
      load_lds16(Kg + (kc << 12) + f, &Ks[f]);
    }
    // stage V chunk transposed (reg-staged, swizzled dest)
    {
      int kv = tid >> 2, ds0 = (tid & 3) << 4;
      const u16* vr = Vg + (kc << 12) + (kv << 6) + ds0;
      u16 tmp[16];
      *(uint4*)&tmp[0] = *(const uint4*)&vr[0];
      *(uint4*)&tmp[8] = *(const uint4*)&vr[8];
      #pragma unroll
      for (int t = 0; t < 16; ++t) {
        int d = ds0 + t;
        int g = (kv >> 3) ^ (d & 7);
        Vt[(d << 6) + (g << 3) + (kv & 7)] = tmp[t];
      }
    }
    __syncthreads();

    // S = Q K^T (wave's 16 q rows x 64 k cols), scaled
    f32x4 s[4] = {};
    #pragma unroll
    for (int kk = 0; kk < 2; ++kk) {
      bf16x8 aq = *(const bf16x8*)&Qs[(wid * 16 + lr) * 64 + kk * 32 + lk * 8];
      #pragma unroll
      for (int ni = 0; ni < 4; ++ni) {
        bf16x8 bk = *(const bf16x8*)&Ks[(ni * 16 + lr) * 64 + kk * 32 + lk * 8];
        s[ni] = __builtin_amdgcn_mfma_f32_16x16x32_bf16(aq, bk, s[ni], 0, 0, 0);
      }
    }
    #pragma unroll
    for (int ni = 0; ni < 4; ++ni) s[ni] = s[ni] * 0.125f;

    // online softmax: row r = lk*4+j, cols across lr (16 lanes) x ni
    float rmax[4];
    #pragma unroll
    for (int j = 0; j < 4; ++j)
      rmax[j] = fmaxf(fmaxf(s[0][j], s[1][j]), fmaxf(s[2][j], s[3][j]));
    #pragma unroll
    for (int off = 1; off < 16; off <<= 1)
      #pragma unroll
      for (int j = 0; j < 4; ++j)
        rmax[j] = fmaxf(rmax[j], __shfl_xor(rmax[j], off, 64));

    float newm[4], alpha[4], rs[4];
    #pragma unroll
    for (int j = 0; j < 4; ++j) {
      newm[j] = fmaxf(m_[j], rmax[j]);
      alpha[j] = __expf(m_[j] - newm[j]);
      rs[j] = 0.f;
    }
    #pragma unroll
    for (int ni = 0; ni < 4; ++ni)
      #pragma unroll
      for (int j = 0; j < 4; ++j) {
        float pv = __expf(s[ni][j] - newm[j]);
        rs[j] += pv;
        Ps[wid][(lk * 4 + j) * 64 + ni * 16 + lr] = f32_to_bf16(pv);
      }
    #pragma unroll
    for (int off = 1; off < 16; off <<= 1)
      #pragma unroll
      for (int j = 0; j < 4; ++j)
        rs[j] += __shfl_xor(rs[j], off, 64);

    f32x4 av;
    #pragma unroll
    for (int j = 0; j < 4; ++j) {
      l_[j] = l_[j] * alpha[j] + rs[j];
      m_[j] = newm[j];
      av[j] = alpha[j];
    }
    #pragma unroll
    for (int ni = 0; ni < 4; ++ni) acc_o[ni] *= av;

    __syncthreads();  // Ps visible (conservative), Vt/Ks fully staged for reads

    // O += P V : A = P[16 q][64 k], B = V[k][d] via swizzled Vt rows
    #pragma unroll
    for (int kk = 0; kk < 2; ++kk) {
      bf16x8 ap = *(const bf16x8*)&Ps[wid][lr * 64 + kk * 32 + lk * 8];
      #pragma unroll
      for (int ni = 0; ni < 4; ++ni) {
        int d = ni * 16 + lr;
        int g = (kk * 4 + lk) ^ (d & 7);
        bf16x8 bv = *(const bf16x8*)&Vt[(d << 6) + (g << 3)];
        acc_o[ni] = __builtin_amdgcn_mfma_f32_16x16x32_bf16(ap, bv, acc_o[ni], 0, 0, 0);
      }
    }
    __syncthreads();  // before restaging Ks/Vt
  }

  // epilogue: normalize, write bf16 to attn_out [tok][c]
  float invl[4];
  #pragma unroll
  for (int j = 0; j < 4; ++j) invl[j] = 1.f / l_[j];
  #pragma unroll
  for (int ni = 0; ni < 4; ++ni)
    #pragma unroll
    for (int j = 0; j < 4; ++j) {
      int qrow = (qt << 6) + wid * 16 + lk * 4 + j;
      int c = h * 64 + ni * 16 + lr;
      out[((size_t)(b * SEQ + qrow)) * CDIM + c] = f32_to_bf16(acc_o[ni][j] * invl[j]);
    }
}

extern "C" void kernel_launch(void* const* d_in, const int* in_sizes, int n_in,
                              void* d_out, int out_size, void* d_ws, size_t ws_size,
                              hipStream_t stream) {
  const float* x     = (const float*)d_in[0];
  const float* w_qkv = (const float*)d_in[1];
  const float* w_o   = (const float*)d_in[2];
  float* out = (float*)d_out;

  u16* xb    = (u16*)d_ws;
  u16* wqkvT = xb    + (size_t)MTOK * CDIM;
  u16* woT   = wqkvT + (size_t)NQKV * CDIM;
  u16* qb    = woT   + (size_t)CDIM * CDIM;
  u16* kb    = qb    + (size_t)NPAIR * SEQ * HD;
  u16* vb    = kb    + (size_t)NPAIR * SEQ * HD;
  u16* ao    = vb    + (size_t)NPAIR * SEQ * HD;

  cvt_x_kernel<<<dim3((MTOK * CDIM) / (256 * 8)), 256, 0, stream>>>(x, xb);
  transpose_cvt_kernel<<<dim3((CDIM * NQKV + 255) / 256), 256, 0, stream>>>(w_qkv, wqkvT, CDIM, NQKV);
  transpose_cvt_kernel<<<dim3((CDIM * CDIM + 255) / 256), 256, 0, stream>>>(w_o, woT, CDIM, CDIM);

  gemm_bt<0><<<dim3((MTOK / 128) * (NQKV / 128)), 256, 0, stream>>>(
      xb, wqkvT, nullptr, qb, kb, vb, MTOK, NQKV, CDIM);

  attn_kernel<<<dim3(NPAIR * 16), 256, 0, stream>>>(qb, kb, vb, ao);

  gemm_bt<1><<<dim3((MTOK / 128) * (CDIM / 128)), 256, 0, stream>>>(
      ao, woT, out, nullptr, nullptr, nullptr, MTOK, CDIM, CDIM);
}

// Round 2
// 206.444 us; speedup vs baseline: 1.0919x; 1.0919x over previous
//
#include <hip/hip_runtime.h>
#include <hip/hip_bf16.h>
#include <stdint.h>

#define SEQ   1024
#define NHEAD 12
#define HD    64
#define CDIM  768
#define MTOK  8192
#define NQKV  2304
#define NPAIR 96   // BS*NHEAD

typedef uint16_t u16;
typedef __attribute__((ext_vector_type(8))) __bf16 bf16x8;
typedef __attribute__((ext_vector_type(4))) float  f32x4;

__device__ __forceinline__ u16 f32_to_bf16(float f) {
  union { float f; uint32_t u; } cv; cv.f = f;
  uint32_t u = cv.u;
  return (u16)((u + 0x7FFFu + ((u >> 16) & 1u)) >> 16);
}

__device__ __forceinline__ void load_lds16(const u16* g, u16* l) {
  __builtin_amdgcn_global_load_lds(
      (const __attribute__((address_space(1))) uint32_t*)g,
      (__attribute__((address_space(3))) uint32_t*)l, 16, 0, 0);
}

// swizzled LDS read: 16B at (row, col-byte cb) of a 128B-row tile
__device__ __forceinline__ bf16x8 ldsw(const u16* base, int r, int cb) {
  int byte = (r << 7) + cb;
  byte ^= ((r & 7) << 4);
  return *(const bf16x8*)((const char*)base + byte);
}

// stage an 8KB tile (64 rows x 128B) from contiguous global, swizzled:
// linear LDS dest, inverse-swizzled global source granule (XOR is involution)
__device__ __forceinline__ void stage_swz(const u16* __restrict__ g, u16* l, int tid) {
  #pragma unroll
  for (int i = 0; i < 2; ++i) {
    int F = i * 4096 + tid * 16;            // byte offset within tile
    int S = F ^ (((F >> 7) & 7) << 4);      // swizzled source byte
    load_lds16(g + (S >> 1), l + (F >> 1));
  }
}

// stage V^T chunk: global vt[pair][d=64][n=1024], take cols kc*64..+63 -> 64x128B tile
__device__ __forceinline__ void stage_vt(const u16* __restrict__ vtb, u16* l, int kc, int tid) {
  #pragma unroll
  for (int i = 0; i < 2; ++i) {
    int F = i * 4096 + tid * 16;
    int S = F ^ (((F >> 7) & 7) << 4);
    int r = S >> 7;                          // == F>>7 (XOR only touches bits 4..6)
    int cb = S & 127;
    load_lds16(vtb + ((size_t)r << 10) + (kc << 6) + (cb >> 1), l + (F >> 1));
  }
}

// ---- convert x (fp32) -> bf16, 8 elems/thread ----
__global__ __launch_bounds__(256) void cvt_x_kernel(const float* __restrict__ in,
                                                    u16* __restrict__ out) {
  int i = blockIdx.x * 256 + threadIdx.x;
  const float4* p = (const float4*)in + (size_t)i * 2;
  float4 a = p[0], b = p[1];
  u16 r[8];
  r[0]=f32_to_bf16(a.x); r[1]=f32_to_bf16(a.y); r[2]=f32_to_bf16(a.z); r[3]=f32_to_bf16(a.w);
  r[4]=f32_to_bf16(b.x); r[5]=f32_to_bf16(b.y); r[6]=f32_to_bf16(b.z); r[7]=f32_to_bf16(b.w);
  uint4 o;
  o.x = (uint32_t)r[0] | ((uint32_t)r[1] << 16);
  o.y = (uint32_t)r[2] | ((uint32_t)r[3] << 16);
  o.z = (uint32_t)r[4] | ((uint32_t)r[5] << 16);
  o.w = (uint32_t)r[6] | ((uint32_t)r[7] << 16);
  ((uint4*)out)[i] = o;
}

// ---- transpose+convert W [K][N] fp32 -> Wt [N][K] bf16 (output-coalesced) ----
__global__ __launch_bounds__(256) void transpose_cvt_kernel(const float* __restrict__ in,
                                                            u16* __restrict__ out,
                                                            int K, int N) {
  int idx = blockIdx.x * 256 + threadIdx.x;
  if (idx >= K * N) return;
  int n = idx / K, k = idx - n * K;
  out[idx] = f32_to_bf16(in[(size_t)k * N + n]);
}

// ---- tiled bf16 GEMM, A[M][K] @ Bt[N][K]^T, 128x128 tile, BK=64, 4 waves ----
// EPI 0: scatter into q (scaled by 0.125) / k [pair][n][d] and vT [pair][d][n]
// EPI 1: plain fp32 store to Cf [M][N]
template<int EPI>
__global__ __launch_bounds__(256) void gemm_bt(const u16* __restrict__ A,
                                               const u16* __restrict__ Bt,
                                               float* __restrict__ Cf,
                                               u16* __restrict__ qb,
                                               u16* __restrict__ kb,
                                               u16* __restrict__ vb,
                                               int M, int N, int K) {
  __shared__ u16 As[128 * 64];
  __shared__ u16 Bs[128 * 64];
  const int ntn = N >> 7;
  int tm = blockIdx.x / ntn, tn = blockIdx.x - tm * ntn;
  int mBase = tm << 7, nBase = tn << 7;
  int tid = threadIdx.x;
  int lane = tid & 63, wid = tid >> 6;
  int wr = (wid >> 1) << 6, wc = (wid & 1) << 6;
  int lr = lane & 15, lk = lane >> 4;

  f32x4 acc[4][4] = {};
  const int nk = K >> 6;
  for (int kt = 0; kt < nk; ++kt) {
    #pragma unroll
    for (int i = 0; i < 4; ++i) {
      int f = i * 2048 + tid * 8;
      int row = f >> 6, col = f & 63;
      load_lds16(A  + (size_t)(mBase + row) * K + kt * 64 + col, &As[f]);
      load_lds16(Bt + (size_t)(nBase + row) * K + kt * 64 + col, &Bs[f]);
    }
    __syncthreads();
    #pragma unroll
    for (int kk = 0; kk < 2; ++kk) {
      bf16x8 af[4], bfr[4];
      #pragma unroll
      for (int i = 0; i < 4; ++i)
        af[i]  = *(const bf16x8*)&As[(wr + i * 16 + lr) * 64 + kk * 32 + lk * 8];
      #pragma unroll
      for (int i = 0; i < 4; ++i)
        bfr[i] = *(const bf16x8*)&Bs[(wc + i * 16 + lr) * 64 + kk * 32 + lk * 8];
      #pragma unroll
      for (int mi = 0; mi < 4; ++mi)
        #pragma unroll
        for (int ni = 0; ni < 4; ++ni)
          acc[mi][ni] = __builtin_amdgcn_mfma_f32_16x16x32_bf16(af[mi], bfr[ni], acc[mi][ni], 0, 0, 0);
    }
    __syncthreads();
  }

  #pragma unroll
  for (int mi = 0; mi < 4; ++mi)
    #pragma unroll
    for (int ni = 0; ni < 4; ++ni)
      #pragma unroll
      for (int j = 0; j < 4; ++j) {
        int m = mBase + wr + mi * 16 + lk * 4 + j;
        int c = nBase + wc + ni * 16 + lr;
        float val = acc[mi][ni][j];
        if (EPI == 0) {
          int s = c / CDIM, rem = c - s * CDIM;
          int h = rem >> 6, d = rem & 63;
          int bb = m >> 10, nn = m & 1023;
          size_t pbase = ((size_t)(bb * NHEAD + h)) << 16;
          if (s == 0)      qb[pbase + (nn << 6) + d] = f32_to_bf16(val * 0.125f);
          else if (s == 1) kb[pbase + (nn << 6) + d] = f32_to_bf16(val);
          else             vb[pbase + ((size_t)d << 10) + nn] = f32_to_bf16(val);
        } else {
          Cf[(size_t)m * N + c] = val;
        }
      }
}

// ---- flash attention: block = (pair, qtile of 64 rows), 4 waves x 16 q-rows ----
// swizzled LDS everywhere; K/V^T double-buffered; 1 barrier per chunk
__global__ __launch_bounds__(256) void attn_kernel(const u16* __restrict__ q,
                                                   const u16* __restrict__ k,
                                                   const u16* __restrict__ v,
                                                   u16* __restrict__ out) {
  __shared__ u16 QPs[64 * 64];      // Q tile, then reused as per-wave P tiles
  __shared__ u16 Ks[2][64 * 64];
  __shared__ u16 Vs[2][64 * 64];    // V^T chunks

  int pair = blockIdx.x >> 4;
  int qt   = blockIdx.x & 15;
  int b = pair / NHEAD, h = pair - b * NHEAD;
  const u16* Qg  = q + ((size_t)pair << 16);
  const u16* Kg  = k + ((size_t)pair << 16);
  const u16* Vtb = v + ((size_t)pair << 16);
  int tid = threadIdx.x, lane = tid & 63, wid = tid >> 6;
  int lr = lane & 15, lk = lane >> 4;

  // prologue: stage Q tile + chunk 0 of K and V^T
  stage_swz(Qg + (qt << 12), QPs, tid);
  stage_swz(Kg, Ks[0], tid);
  stage_vt(Vtb, Vs[0], 0, tid);
  __syncthreads();

  // hoist Q fragments to registers (QPs LDS is then reused as P storage)
  bf16x8 aq[2];
  aq[0] = ldsw(QPs, wid * 16 + lr, lk * 16);
  aq[1] = ldsw(QPs, wid * 16 + lr, 64 + lk * 16);

  float m_[4], l_[4];
  #pragma unroll
  for (int j = 0; j < 4; ++j) { m_[j] = -1e30f; l_[j] = 0.f; }
  f32x4 acc_o[4] = {};

  for (int kc = 0; kc < 16; ++kc) {
    const int cur = kc & 1;
    // prefetch next chunk into the other buffer
    if (kc < 15) {
      stage_swz(Kg + ((kc + 1) << 12), Ks[cur ^ 1], tid);
      stage_vt(Vtb, Vs[cur ^ 1], kc + 1, tid);
    }

    // S = Q K^T  (scale already folded into q)
    f32x4 s[4] = {};
    #pragma unroll
    for (int kk = 0; kk < 2; ++kk)
      #pragma unroll
      for (int ni = 0; ni < 4; ++ni) {
        bf16x8 bk = ldsw(Ks[cur], ni * 16 + lr, kk * 64 + lk * 16);
        s[ni] = __builtin_amdgcn_mfma_f32_16x16x32_bf16(aq[kk], bk, s[ni], 0, 0, 0);
      }

    // online softmax: row r = lk*4+j held across the 16 lr lanes
    float rmax[4];
    #pragma unroll
    for (int j = 0; j < 4; ++j)
      rmax[j] = fmaxf(fmaxf(s[0][j], s[1][j]), fmaxf(s[2][j], s[3][j]));
    #pragma unroll
    for (int off = 1; off < 16; off <<= 1)
      #pragma unroll
      for (int j = 0; j < 4; ++j)
        rmax[j] = fmaxf(rmax[j], __shfl_xor(rmax[j], off, 64));

    float newm[4], alpha[4], rs[4];
    #pragma unroll
    for (int j = 0; j < 4; ++j) {
      newm[j] = fmaxf(m_[j], rmax[j]);
      alpha[j] = __expf(m_[j] - newm[j]);
      rs[j] = 0.f;
    }
    #pragma unroll
    for (int ni = 0; ni < 4; ++ni)
      #pragma unroll
      for (int j = 0; j < 4; ++j) {
        float pv = __expf(s[ni][j] - newm[j]);
        rs[j] += pv;
        int row = lk * 4 + j;
        int byte = (wid << 11) + (row << 7) + ((ni * 16 + lr) << 1);
        byte ^= ((row & 7) << 4);
        *(u16*)((char*)QPs + byte) = f32_to_bf16(pv);
      }
    #pragma unroll
    for (int off = 1; off < 16; off <<= 1)
      #pragma unroll
      for (int j = 0; j < 4; ++j)
        rs[j] += __shfl_xor(rs[j], off, 64);

    f32x4 av;
    #pragma unroll
    for (int j = 0; j < 4; ++j) {
      l_[j] = l_[j] * alpha[j] + rs[j];
      m_[j] = newm[j];
      av[j] = alpha[j];
    }
    #pragma unroll
    for (int ni = 0; ni < 4; ++ni) acc_o[ni] *= av;

    // O += P V : wave-private P exchange through LDS (in-order DS pipe, no barrier)
    #pragma unroll
    for (int kk = 0; kk < 2; ++kk) {
      bf16x8 ap = ldsw(QPs + wid * 1024, lr, kk * 64 + lk * 16);
      #pragma unroll
      for (int ni = 0; ni < 4; ++ni) {
        bf16x8 bv = ldsw(Vs[cur], ni * 16 + lr, kk * 64 + lk * 16);
        acc_o[ni] = __builtin_amdgcn_mfma_f32_16x16x32_bf16(ap, bv, acc_o[ni], 0, 0, 0);
      }
    }
    __syncthreads();   // reads of buf[cur] done + prefetched loads drained
  }

  // epilogue: normalize, write bf16 to attn_out [tok][c]
  float invl[4];
  #pragma unroll
  for (int j = 0; j < 4; ++j) invl[j] = 1.f / l_[j];
  #pragma unroll
  for (int ni = 0; ni < 4; ++ni)
    #pragma unroll
    for (int j = 0; j < 4; ++j) {
      int qrow = (qt << 6) + wid * 16 + lk * 4 + j;
      int c = h * 64 + ni * 16 + lr;
      out[((size_t)(b * SEQ + qrow)) * CDIM + c] = f32_to_bf16(acc_o[ni][j] * invl[j]);
    }
}

extern "C" void kernel_launch(void* const* d_in, const int* in_sizes, int n_in,
                              void* d_out, int out_size, void* d_ws, size_t ws_size,
                              hipStream_t stream) {
  const float* x     = (const float*)d_in[0];
  const float* w_qkv = (const float*)d_in[1];
  const float* w_o   = (const float*)d_in[2];
  float* out = (float*)d_out;

  u16* xb    = (u16*)d_ws;
  u16* wqkvT = xb    + (size_t)MTOK * CDIM;
  u16* woT   = wqkvT + (size_t)NQKV * CDIM;
  u16* qb    = woT   + (size_t)CDIM * CDIM;
  u16* kb    = qb    + (size_t)NPAIR * SEQ * HD;
  u16* vb    = kb    + (size_t)NPAIR * SEQ * HD;   // stored transposed: [pair][d][n]
  u16* ao    = vb    + (size_t)NPAIR * SEQ * HD;

  cvt_x_kernel<<<dim3((MTOK * CDIM) / (256 * 8)), 256, 0, stream>>>(x, xb);
  transpose_cvt_kernel<<<dim3((CDIM * NQKV + 255) / 256), 256, 0, stream>>>(w_qkv, wqkvT, CDIM, NQKV);
  transpose_cvt_kernel<<<dim3((CDIM * CDIM + 255) / 256), 256, 0, stream>>>(w_o, woT, CDIM, CDIM);

  gemm_bt<0><<<dim3((MTOK / 128) * (NQKV / 128)), 256, 0, stream>>>(
      xb, wqkvT, nullptr, qb, kb, vb, MTOK, NQKV, CDIM);

  attn_kernel<<<dim3(NPAIR * 16), 256, 0, stream>>>(qb, kb, vb, ao);

  gemm_bt<1><<<dim3((MTOK / 128) * (CDIM / 128)), 256, 0, stream>>>(
      ao, woT, out, nullptr, nullptr, nullptr, MTOK, CDIM, CDIM);
}

// Round 3
// 191.079 us; speedup vs baseline: 1.1797x; 1.0804x over previous
//
#include <hip/hip_runtime.h>
#include <hip/hip_bf16.h>
#include <stdint.h>
#include <math.h>

#define SEQ   1024
#define NHEAD 12
#define HD    64
#define CDIM  768
#define MTOK  8192
#define NQKV  2304
#define NPAIR 96   // BS*NHEAD

// q pre-scale: 1/sqrt(64) * log2(e)  (softmax done base-2)
#define QSCALE 0.18033688011112042f

typedef uint16_t u16;
typedef __attribute__((ext_vector_type(8))) __bf16 bf16x8;
typedef __attribute__((ext_vector_type(4))) float  f32x4;

__device__ __forceinline__ u16 f32_to_bf16(float f) {
  union { float f; uint32_t u; } cv; cv.f = f;
  uint32_t u = cv.u;
  return (u16)((u + 0x7FFFu + ((u >> 16) & 1u)) >> 16);
}

__device__ __forceinline__ uint32_t cvt_pk_bf16(float lo, float hi) {
  uint32_t r;
  asm("v_cvt_pk_bf16_f32 %0, %1, %2" : "=v"(r) : "v"(lo), "v"(hi));
  return r;
}

__device__ __forceinline__ void load_lds16(const u16* g, u16* l) {
  __builtin_amdgcn_global_load_lds(
      (const __attribute__((address_space(1))) uint32_t*)g,
      (__attribute__((address_space(3))) uint32_t*)l, 16, 0, 0);
}

// swizzled LDS read: 16B at (row, col-byte cb) of a 128B-row tile
__device__ __forceinline__ bf16x8 ldsw(const u16* base, int r, int cb) {
  int byte = (r << 7) + cb;
  byte ^= ((r & 7) << 4);
  return *(const bf16x8*)((const char*)base + byte);
}

// stage an 8KB tile (64 rows x 128B) from contiguous global, swizzled:
// linear LDS dest, inverse-swizzled global source granule (XOR is involution)
__device__ __forceinline__ void stage_swz(const u16* __restrict__ g, u16* l, int tid) {
  #pragma unroll
  for (int i = 0; i < 2; ++i) {
    int F = i * 4096 + tid * 16;            // byte offset within tile
    int S = F ^ (((F >> 7) & 7) << 4);      // swizzled source byte
    load_lds16(g + (S >> 1), l + (F >> 1));
  }
}

// stage V^T chunk: global vt[pair][d=64][n=1024], take cols kc*64..+63 -> 64x128B tile
__device__ __forceinline__ void stage_vt(const u16* __restrict__ vtb, u16* l, int kc, int tid) {
  #pragma unroll
  for (int i = 0; i < 2; ++i) {
    int F = i * 4096 + tid * 16;
    int S = F ^ (((F >> 7) & 7) << 4);
    int r = S >> 7;                          // == F>>7 (XOR only touches bits 4..6)
    int cb = S & 127;
    load_lds16(vtb + ((size_t)r << 10) + (kc << 6) + (cb >> 1), l + (F >> 1));
  }
}

// ---- convert x (fp32) -> bf16, 8 elems/thread ----
__global__ __launch_bounds__(256) void cvt_x_kernel(const float* __restrict__ in,
                                                    u16* __restrict__ out) {
  int i = blockIdx.x * 256 + threadIdx.x;
  const float4* p = (const float4*)in + (size_t)i * 2;
  float4 a = p[0], b = p[1];
  uint4 o;
  o.x = cvt_pk_bf16(a.x, a.y);
  o.y = cvt_pk_bf16(a.z, a.w);
  o.z = cvt_pk_bf16(b.x, b.y);
  o.w = cvt_pk_bf16(b.z, b.w);
  ((uint4*)out)[i] = o;
}

// ---- transpose+convert W [K][N] fp32 -> Wt [N][K] bf16 (output-coalesced) ----
__global__ __launch_bounds__(256) void transpose_cvt_kernel(const float* __restrict__ in,
                                                            u16* __restrict__ out,
                                                            int K, int N) {
  int idx = blockIdx.x * 256 + threadIdx.x;
  if (idx >= K * N) return;
  int n = idx / K, k = idx - n * K;
  out[idx] = f32_to_bf16(in[(size_t)k * N + n]);
}

// ---- tiled bf16 GEMM, A[M][K] @ Bt[N][K]^T, 128x128 tile, BK=64, 4 waves ----
// EPI 0: scatter into q (pre-scaled) / k [pair][n][d] and vT [pair][d][n]
// EPI 1: plain fp32 store to Cf [M][N]
template<int EPI>
__global__ __launch_bounds__(256) void gemm_bt(const u16* __restrict__ A,
                                               const u16* __restrict__ Bt,
                                               float* __restrict__ Cf,
                                               u16* __restrict__ qb,
                                               u16* __restrict__ kb,
                                               u16* __restrict__ vb,
                                               int M, int N, int K) {
  __shared__ u16 As[128 * 64];
  __shared__ u16 Bs[128 * 64];
  const int ntn = N >> 7;
  int tm = blockIdx.x / ntn, tn = blockIdx.x - tm * ntn;
  int mBase = tm << 7, nBase = tn << 7;
  int tid = threadIdx.x;
  int lane = tid & 63, wid = tid >> 6;
  int wr = (wid >> 1) << 6, wc = (wid & 1) << 6;
  int lr = lane & 15, lk = lane >> 4;

  f32x4 acc[4][4] = {};
  const int nk = K >> 6;
  for (int kt = 0; kt < nk; ++kt) {
    #pragma unroll
    for (int i = 0; i < 4; ++i) {
      int f = i * 2048 + tid * 8;
      int row = f >> 6, col = f & 63;
      load_lds16(A  + (size_t)(mBase + row) * K + kt * 64 + col, &As[f]);
      load_lds16(Bt + (size_t)(nBase + row) * K + kt * 64 + col, &Bs[f]);
    }
    __syncthreads();
    #pragma unroll
    for (int kk = 0; kk < 2; ++kk) {
      bf16x8 af[4], bfr[4];
      #pragma unroll
      for (int i = 0; i < 4; ++i)
        af[i]  = *(const bf16x8*)&As[(wr + i * 16 + lr) * 64 + kk * 32 + lk * 8];
      #pragma unroll
      for (int i = 0; i < 4; ++i)
        bfr[i] = *(const bf16x8*)&Bs[(wc + i * 16 + lr) * 64 + kk * 32 + lk * 8];
      #pragma unroll
      for (int mi = 0; mi < 4; ++mi)
        #pragma unroll
        for (int ni = 0; ni < 4; ++ni)
          acc[mi][ni] = __builtin_amdgcn_mfma_f32_16x16x32_bf16(af[mi], bfr[ni], acc[mi][ni], 0, 0, 0);
    }
    __syncthreads();
  }

  #pragma unroll
  for (int mi = 0; mi < 4; ++mi)
    #pragma unroll
    for (int ni = 0; ni < 4; ++ni)
      #pragma unroll
      for (int j = 0; j < 4; ++j) {
        int m = mBase + wr + mi * 16 + lk * 4 + j;
        int c = nBase + wc + ni * 16 + lr;
        float val = acc[mi][ni][j];
        if (EPI == 0) {
          int s = c / CDIM, rem = c - s * CDIM;
          int h = rem >> 6, d = rem & 63;
          int bb = m >> 10, nn = m & 1023;
          size_t pbase = ((size_t)(bb * NHEAD + h)) << 16;
          if (s == 0)      qb[pbase + (nn << 6) + d] = f32_to_bf16(val * QSCALE);
          else if (s == 1) kb[pbase + (nn << 6) + d] = f32_to_bf16(val);
          else             vb[pbase + ((size_t)d << 10) + nn] = f32_to_bf16(val);
        } else {
          Cf[(size_t)m * N + c] = val;
        }
      }
}

// ---- flash attention: block = (pair, qtile of 64 rows), 4 waves x 16 q-rows ----
// swapped QK^T (lane holds one q-column, 16 k-values) -> in-lane softmax,
// cvt_pk P-pack, wave-private swizzled LDS P exchange; 1 barrier per chunk
__global__ __launch_bounds__(256) void attn_kernel(const u16* __restrict__ q,
                                                   const u16* __restrict__ k,
                                                   const u16* __restrict__ v,
                                                   u16* __restrict__ out) {
  __shared__ u16 QPs[64 * 64];      // Q tile, then per-wave P tiles (2KB/wave)
  __shared__ u16 Ks[2][64 * 64];
  __shared__ u16 Vs[2][64 * 64];    // V^T chunks

  int pair = blockIdx.x >> 4;
  int qt   = blockIdx.x & 15;
  int b = pair / NHEAD, h = pair - b * NHEAD;
  const u16* Qg  = q + ((size_t)pair << 16);
  const u16* Kg  = k + ((size_t)pair << 16);
  const u16* Vtb = v + ((size_t)pair << 16);
  int tid = threadIdx.x, lane = tid & 63, wid = tid >> 6;
  int lr = lane & 15, lk = lane >> 4;

  // prologue: stage Q tile + chunk 0 of K and V^T
  stage_swz(Qg + (qt << 12), QPs, tid);
  stage_swz(Kg, Ks[0], tid);
  stage_vt(Vtb, Vs[0], 0, tid);
  __syncthreads();

  // hoist Q fragments to registers; QPs then reused as wave-private P storage
  // (wave w only ever touches QPs rows [w*16, w*16+16) == its own 2KB region)
  bf16x8 aq[2];
  aq[0] = ldsw(QPs, wid * 16 + lr, lk * 16);
  aq[1] = ldsw(QPs, wid * 16 + lr, 64 + lk * 16);
  u16* Pa = QPs + wid * 1024;

  float m_ = -1e30f, l_ = 0.f;
  f32x4 acc_o[4] = {};

  for (int kc = 0; kc < 16; ++kc) {
    const int cur = kc & 1;
    // prefetch next chunk into the other buffer (flies during compute)
    if (kc < 15) {
      stage_swz(Kg + ((kc + 1) << 12), Ks[cur ^ 1], tid);
      stage_vt(Vtb, Vs[cur ^ 1], kc + 1, tid);
    }

    // S^T = K Q^T : lane holds q = wid*16+lr, k = ni*16 + lk*4 + j
    f32x4 s[4] = {};
    #pragma unroll
    for (int kk = 0; kk < 2; ++kk)
      #pragma unroll
      for (int ni = 0; ni < 4; ++ni) {
        bf16x8 ak = ldsw(Ks[cur], ni * 16 + lr, kk * 64 + lk * 16);
        s[ni] = __builtin_amdgcn_mfma_f32_16x16x32_bf16(ak, aq[kk], s[ni], 0, 0, 0);
      }

    // in-lane row stats over 16 values, then reduce across the 4 dup lanes
    float mx01 = fmaxf(fmaxf(s[0][0], s[0][1]), fmaxf(s[0][2], s[0][3]));
    float mx23 = fmaxf(fmaxf(s[1][0], s[1][1]), fmaxf(s[1][2], s[1][3]));
    float mx45 = fmaxf(fmaxf(s[2][0], s[2][1]), fmaxf(s[2][2], s[2][3]));
    float mx67 = fmaxf(fmaxf(s[3][0], s[3][1]), fmaxf(s[3][2], s[3][3]));
    float mx = fmaxf(fmaxf(mx01, mx23), fmaxf(mx45, mx67));
    mx = fmaxf(mx, __shfl_xor(mx, 16, 64));
    mx = fmaxf(mx, __shfl_xor(mx, 32, 64));

    float newm = fmaxf(m_, mx);
    float alpha = exp2f(m_ - newm);
    m_ = newm;

    f32x4 e[4];
    #pragma unroll
    for (int ni = 0; ni < 4; ++ni)
      #pragma unroll
      for (int j = 0; j < 4; ++j)
        e[ni][j] = exp2f(s[ni][j] - newm);

    float rs0 = (e[0][0] + e[0][1]) + (e[0][2] + e[0][3]);
    float rs1 = (e[1][0] + e[1][1]) + (e[1][2] + e[1][3]);
    float rs2 = (e[2][0] + e[2][1]) + (e[2][2] + e[2][3]);
    float rs3 = (e[3][0] + e[3][1]) + (e[3][2] + e[3][3]);
    float rs = (rs0 + rs1) + (rs2 + rs3);
    rs += __shfl_xor(rs, 16, 64);
    rs += __shfl_xor(rs, 32, 64);
    l_ = l_ * alpha + rs;

    // pack P row (q=lr) into wave-private LDS: row lr, k = ni*16 + lk*4 .. +3
    #pragma unroll
    for (int ni = 0; ni < 4; ++ni) {
      uint32_t w0 = cvt_pk_bf16(e[ni][0], e[ni][1]);
      uint32_t w1 = cvt_pk_bf16(e[ni][2], e[ni][3]);
      int byte = (lr << 7) + (ni << 5) + (lk << 3);
      byte ^= ((lr & 7) << 4);
      uint2 wv; wv.x = w0; wv.y = w1;
      *(uint2*)((char*)Pa + byte) = wv;
    }

    // broadcast alpha to accumulator rows (row j holds q = wid*16 + lk*4 + j)
    f32x4 av;
    #pragma unroll
    for (int j = 0; j < 4; ++j) av[j] = __shfl(alpha, lk * 4 + j, 64);
    #pragma unroll
    for (int ni = 0; ni < 4; ++ni) acc_o[ni] *= av;

    // O += P V : A-frag = P[q=lr][k] from wave-private Pa (in-order DS pipe)
    #pragma unroll
    for (int kk = 0; kk < 2; ++kk) {
      bf16x8 ap = ldsw(Pa, lr, kk * 64 + lk * 16);
      #pragma unroll
      for (int ni = 0; ni < 4; ++ni) {
        bf16x8 bv = ldsw(Vs[cur], ni * 16 + lr, kk * 64 + lk * 16);
        acc_o[ni] = __builtin_amdgcn_mfma_f32_16x16x32_bf16(ap, bv, acc_o[ni], 0, 0, 0);
      }
    }
    __syncthreads();   // reads of buf[cur] done + prefetched loads drained
  }

  // epilogue: normalize (invl lives in lane lr'=row), write bf16 attn_out [tok][c]
  float il = 1.f / l_;
  f32x4 ilv;
  #pragma unroll
  for (int j = 0; j < 4; ++j) ilv[j] = __shfl(il, lk * 4 + j, 64);
  #pragma unroll
  for (int ni = 0; ni < 4; ++ni)
    #pragma unroll
    for (int j = 0; j < 4; ++j) {
      int qrow = (qt << 6) + wid * 16 + lk * 4 + j;
      int c = h * 64 + ni * 16 + lr;
      out[((size_t)(b * SEQ + qrow)) * CDIM + c] = f32_to_bf16(acc_o[ni][j] * ilv[j]);
    }
}

extern "C" void kernel_launch(void* const* d_in, const int* in_sizes, int n_in,
                              void* d_out, int out_size, void* d_ws, size_t ws_size,
                              hipStream_t stream) {
  const float* x     = (const float*)d_in[0];
  const float* w_qkv = (const float*)d_in[1];
  const float* w_o   = (const float*)d_in[2];
  float* out = (float*)d_out;

  u16* xb    = (u16*)d_ws;
  u16* wqkvT = xb    + (size_t)MTOK * CDIM;
  u16* woT   = wqkvT + (size_t)NQKV * CDIM;
  u16* qb    = woT   + (size_t)CDIM * CDIM;
  u16* kb    = qb    + (size_t)NPAIR * SEQ * HD;
  u16* vb    = kb    + (size_t)NPAIR * SEQ * HD;   // stored transposed: [pair][d][n]
  u16* ao    = vb    + (size_t)NPAIR * SEQ * HD;

  cvt_x_kernel<<<dim3((MTOK * CDIM) / (256 * 8)), 256, 0, stream>>>(x, xb);
  transpose_cvt_kernel<<<dim3((CDIM * NQKV + 255) / 256), 256, 0, stream>>>(w_qkv, wqkvT, CDIM, NQKV);
  transpose_cvt_kernel<<<dim3((CDIM * CDIM + 255) / 256), 256, 0, stream>>>(w_o, woT, CDIM, CDIM);

  gemm_bt<0><<<dim3((MTOK / 128) * (NQKV / 128)), 256, 0, stream>>>(
      xb, wqkvT, nullptr, qb, kb, vb, MTOK, NQKV, CDIM);

  attn_kernel<<<dim3(NPAIR * 16), 256, 0, stream>>>(qb, kb, vb, ao);

  gemm_bt<1><<<dim3((MTOK / 128) * (CDIM / 128)), 256, 0, stream>>>(
      ao, woT, out, nullptr, nullptr, nullptr, MTOK, CDIM, CDIM);
}

// Round 4
// 157.472 us; speedup vs baseline: 1.4315x; 1.2134x over previous
//
#include <hip/hip_runtime.h>
#include <hip/hip_bf16.h>
#include <stdint.h>
#include <math.h>

#define SEQ   1024
#define NHEAD 12
#define HD    64
#define CDIM  768
#define MTOK  8192
#define NQKV  2304
#define NPAIR 96   // BS*NHEAD

// q pre-scale: 1/sqrt(64) * log2(e)  (softmax done base-2)
#define QSCALE 0.18033688011112042f

typedef uint16_t u16;
typedef __attribute__((ext_vector_type(8))) __bf16 bf16x8;
typedef __attribute__((ext_vector_type(4))) float  f32x4;

__device__ __forceinline__ u16 f32_to_bf16(float f) {
  union { float f; uint32_t u; } cv; cv.f = f;
  uint32_t u = cv.u;
  return (u16)((u + 0x7FFFu + ((u >> 16) & 1u)) >> 16);
}

__device__ __forceinline__ uint32_t cvt_pk_bf16(float lo, float hi) {
  uint32_t r;
  asm("v_cvt_pk_bf16_f32 %0, %1, %2" : "=v"(r) : "v"(lo), "v"(hi));
  return r;
}

__device__ __forceinline__ void load_lds16(const u16* g, u16* l) {
  __builtin_amdgcn_global_load_lds(
      (const __attribute__((address_space(1))) uint32_t*)g,
      (__attribute__((address_space(3))) uint32_t*)l, 16, 0, 0);
}

// swizzled LDS read: 16B at (row, col-byte cb) of a 128B-row tile
__device__ __forceinline__ bf16x8 ldsw(const u16* base, int r, int cb) {
  int byte = (r << 7) + cb;
  byte ^= ((r & 7) << 4);
  return *(const bf16x8*)((const char*)base + byte);
}

// stage an 8KB tile (64 rows x 128B) from contiguous global, swizzled
__device__ __forceinline__ void stage_swz(const u16* __restrict__ g, u16* l, int tid) {
  #pragma unroll
  for (int i = 0; i < 2; ++i) {
    int F = i * 4096 + tid * 16;
    int S = F ^ (((F >> 7) & 7) << 4);
    load_lds16(g + (S >> 1), l + (F >> 1));
  }
}

// stage V^T chunk: global vt[pair][d=64][n=1024], cols kc*64..+63 -> 64x128B tile
__device__ __forceinline__ void stage_vt(const u16* __restrict__ vtb, u16* l, int kc, int tid) {
  #pragma unroll
  for (int i = 0; i < 2; ++i) {
    int F = i * 4096 + tid * 16;
    int S = F ^ (((F >> 7) & 7) << 4);
    int r = S >> 7;
    int cb = S & 127;
    load_lds16(vtb + ((size_t)r << 10) + (kc << 6) + (cb >> 1), l + (F >> 1));
  }
}

// ---- convert x (fp32) -> bf16, 8 elems/thread ----
__global__ __launch_bounds__(256) void cvt_x_kernel(const float* __restrict__ in,
                                                    u16* __restrict__ out) {
  int i = blockIdx.x * 256 + threadIdx.x;
  const float4* p = (const float4*)in + (size_t)i * 2;
  float4 a = p[0], b = p[1];
  uint4 o;
  o.x = cvt_pk_bf16(a.x, a.y);
  o.y = cvt_pk_bf16(a.z, a.w);
  o.z = cvt_pk_bf16(b.x, b.y);
  o.w = cvt_pk_bf16(b.z, b.w);
  ((uint4*)out)[i] = o;
}

// ---- LDS-tiled transpose+convert: in [K][N] fp32 -> out [N][K] bf16 ----
// 64x64 tiles, coalesced global read and write, pad-66 LDS (2-way = free)
__global__ __launch_bounds__(256) void transpose_cvt_kernel(const float* __restrict__ in,
                                                            u16* __restrict__ out,
                                                            int K, int N) {
  __shared__ u16 t[64][66];
  int nbk = K >> 6;
  int bk = blockIdx.x % nbk, bn = blockIdx.x / nbk;
  int k0 = bk << 6, n0 = bn << 6;
  int tid = threadIdx.x;
  #pragma unroll
  for (int i = 0; i < 16; ++i) {
    int idx = i * 256 + tid;
    int kr = idx >> 6, nc = idx & 63;
    t[kr][nc] = f32_to_bf16(in[(size_t)(k0 + kr) * N + n0 + nc]);
  }
  __syncthreads();
  #pragma unroll
  for (int i = 0; i < 16; ++i) {
    int idx = i * 256 + tid;
    int nr = idx >> 6, kc = idx & 63;
    out[(size_t)(n0 + nr) * K + k0 + kc] = t[kc][nr];
  }
}

// ---- bf16 GEMM, A[M][K] @ Bt[N][K]^T, 128x128 tile, BK=64, 4 waves ----
// Double-buffered LDS + counted vmcnt (loads in flight across barriers),
// T2 read swizzle, T1 XCD-chunked block order (tm-major per XCD).
// EPI 0: scatter into q (pre-scaled) / k [pair][n][d] and vT [pair][d][n]
// EPI 1: plain fp32 store to Cf [M][N]
template<int EPI>
__global__ __launch_bounds__(256) void gemm_bt(const u16* __restrict__ A,
                                               const u16* __restrict__ Bt,
                                               float* __restrict__ Cf,
                                               u16* __restrict__ qb,
                                               u16* __restrict__ kb,
                                               u16* __restrict__ vb,
                                               int M, int N, int K, int cpx) {
  __shared__ u16 As[2][128 * 64];
  __shared__ u16 Bs[2][128 * 64];

  // bijective XCD swizzle (gridDim.x % 8 == 0)
  int bid = blockIdx.x;
  int wgid = (bid & 7) * cpx + (bid >> 3);
  const int ntn = N >> 7;
  int tm = wgid / ntn, tn = wgid - tm * ntn;
  int mBase = tm << 7, nBase = tn << 7;
  int tid = threadIdx.x;
  int lane = tid & 63, wid = tid >> 6;
  int wr = (wid >> 1) << 6, wc = (wid & 1) << 6;
  int lr = lane & 15, lk = lane >> 4;

  const int nk = K >> 6;

  // stage K-tile kt into buffer b: linear LDS dest, source column pre-swizzled
  auto STAGE = [&](int kt, int b) {
    #pragma unroll
    for (int i = 0; i < 4; ++i) {
      int F = i * 4096 + tid * 16;            // byte within 16KB tile
      int row = F >> 7;                       // 0..127
      int cb  = (F & 127) ^ ((row & 7) << 4); // pre-swizzled source column byte
      load_lds16(A + (size_t)(mBase + row) * K + kt * 64 + (cb >> 1), &As[b][F >> 1]);
    }
    #pragma unroll
    for (int i = 0; i < 4; ++i) {
      int F = i * 4096 + tid * 16;
      int row = F >> 7;
      int cb  = (F & 127) ^ ((row & 7) << 4);
      load_lds16(Bt + (size_t)(nBase + row) * K + kt * 64 + (cb >> 1), &Bs[b][F >> 1]);
    }
  };

  f32x4 acc[4][4] = {};

  STAGE(0, 0);
  for (int kt = 0; kt < nk; ++kt) {
    const int cur = kt & 1;
    if (kt + 1 < nk) {
      STAGE(kt + 1, cur ^ 1);
      asm volatile("s_waitcnt vmcnt(8)" ::: "memory");   // buf[cur] landed; next tile in flight
    } else {
      asm volatile("s_waitcnt vmcnt(0)" ::: "memory");
    }
    __builtin_amdgcn_s_barrier();
    asm volatile("" ::: "memory");   // keep ds_reads below the barrier

    #pragma unroll
    for (int kk = 0; kk < 2; ++kk) {
      bf16x8 af[4], bfr[4];
      #pragma unroll
      for (int i = 0; i < 4; ++i)
        af[i]  = ldsw(As[cur], wr + i * 16 + lr, kk * 64 + lk * 16);
      #pragma unroll
      for (int i = 0; i < 4; ++i)
        bfr[i] = ldsw(Bs[cur], wc + i * 16 + lr, kk * 64 + lk * 16);
      #pragma unroll
      for (int mi = 0; mi < 4; ++mi)
        #pragma unroll
        for (int ni = 0; ni < 4; ++ni)
          acc[mi][ni] = __builtin_amdgcn_mfma_f32_16x16x32_bf16(af[mi], bfr[ni], acc[mi][ni], 0, 0, 0);
    }

    __builtin_amdgcn_s_barrier();    // reads of buf[cur] done before next STAGE overwrites
    asm volatile("" ::: "memory");   // keep next STAGE below this barrier
  }

  #pragma unroll
  for (int mi = 0; mi < 4; ++mi)
    #pragma unroll
    for (int ni = 0; ni < 4; ++ni)
      #pragma unroll
      for (int j = 0; j < 4; ++j) {
        int m = mBase + wr + mi * 16 + lk * 4 + j;
        int c = nBase + wc + ni * 16 + lr;
        float val = acc[mi][ni][j];
        if (EPI == 0) {
          int s = c / CDIM, rem = c - s * CDIM;
          int h = rem >> 6, d = rem & 63;
          int bb = m >> 10, nn = m & 1023;
          size_t pbase = ((size_t)(bb * NHEAD + h)) << 16;
          if (s == 0)      qb[pbase + (nn << 6) + d] = f32_to_bf16(val * QSCALE);
          else if (s == 1) kb[pbase + (nn << 6) + d] = f32_to_bf16(val);
          else             vb[pbase + ((size_t)d << 10) + nn] = f32_to_bf16(val);
        } else {
          Cf[(size_t)m * N + c] = val;
        }
      }
}

// ---- flash attention: block = (pair, qtile of 64 rows), 4 waves x 16 q-rows ----
__global__ __launch_bounds__(256) void attn_kernel(const u16* __restrict__ q,
                                                   const u16* __restrict__ k,
                                                   const u16* __restrict__ v,
                                                   u16* __restrict__ out) {
  __shared__ u16 QPs[64 * 64];      // Q tile, then per-wave P tiles (2KB/wave)
  __shared__ u16 Ks[2][64 * 64];
  __shared__ u16 Vs[2][64 * 64];    // V^T chunks

  int pair = blockIdx.x >> 4;
  int qt   = blockIdx.x & 15;
  int b = pair / NHEAD, h = pair - b * NHEAD;
  const u16* Qg  = q + ((size_t)pair << 16);
  const u16* Kg  = k + ((size_t)pair << 16);
  const u16* Vtb = v + ((size_t)pair << 16);
  int tid = threadIdx.x, lane = tid & 63, wid = tid >> 6;
  int lr = lane & 15, lk = lane >> 4;

  stage_swz(Qg + (qt << 12), QPs, tid);
  stage_swz(Kg, Ks[0], tid);
  stage_vt(Vtb, Vs[0], 0, tid);
  __syncthreads();

  bf16x8 aq[2];
  aq[0] = ldsw(QPs, wid * 16 + lr, lk * 16);
  aq[1] = ldsw(QPs, wid * 16 + lr, 64 + lk * 16);
  u16* Pa = QPs + wid * 1024;

  float m_ = -1e30f, l_ = 0.f;
  f32x4 acc_o[4] = {};

  for (int kc = 0; kc < 16; ++kc) {
    const int cur = kc & 1;
    if (kc < 15) {
      stage_swz(Kg + ((kc + 1) << 12), Ks[cur ^ 1], tid);
      stage_vt(Vtb, Vs[cur ^ 1], kc + 1, tid);
    }

    // S^T = K Q^T : lane holds q = wid*16+lr, k = ni*16 + lk*4 + j
    f32x4 s[4] = {};
    #pragma unroll
    for (int kk = 0; kk < 2; ++kk)
      #pragma unroll
      for (int ni = 0; ni < 4; ++ni) {
        bf16x8 ak = ldsw(Ks[cur], ni * 16 + lr, kk * 64 + lk * 16);
        s[ni] = __builtin_amdgcn_mfma_f32_16x16x32_bf16(ak, aq[kk], s[ni], 0, 0, 0);
      }

    float mx01 = fmaxf(fmaxf(s[0][0], s[0][1]), fmaxf(s[0][2], s[0][3]));
    float mx23 = fmaxf(fmaxf(s[1][0], s[1][1]), fmaxf(s[1][2], s[1][3]));
    float mx45 = fmaxf(fmaxf(s[2][0], s[2][1]), fmaxf(s[2][2], s[2][3]));
    float mx67 = fmaxf(fmaxf(s[3][0], s[3][1]), fmaxf(s[3][2], s[3][3]));
    float mx = fmaxf(fmaxf(mx01, mx23), fmaxf(mx45, mx67));
    mx = fmaxf(mx, __shfl_xor(mx, 16, 64));
    mx = fmaxf(mx, __shfl_xor(mx, 32, 64));

    float newm = fmaxf(m_, mx);
    float alpha = exp2f(m_ - newm);
    m_ = newm;

    f32x4 e[4];
    #pragma unroll
    for (int ni = 0; ni < 4; ++ni)
      #pragma unroll
      for (int j = 0; j < 4; ++j)
        e[ni][j] = exp2f(s[ni][j] - newm);

    float rs0 = (e[0][0] + e[0][1]) + (e[0][2] + e[0][3]);
    float rs1 = (e[1][0] + e[1][1]) + (e[1][2] + e[1][3]);
    float rs2 = (e[2][0] + e[2][1]) + (e[2][2] + e[2][3]);
    float rs3 = (e[3][0] + e[3][1]) + (e[3][2] + e[3][3]);
    float rs = (rs0 + rs1) + (rs2 + rs3);
    rs += __shfl_xor(rs, 16, 64);
    rs += __shfl_xor(rs, 32, 64);
    l_ = l_ * alpha + rs;

    #pragma unroll
    for (int ni = 0; ni < 4; ++ni) {
      uint32_t w0 = cvt_pk_bf16(e[ni][0], e[ni][1]);
      uint32_t w1 = cvt_pk_bf16(e[ni][2], e[ni][3]);
      int byte = (lr << 7) + (ni << 5) + (lk << 3);
      byte ^= ((lr & 7) << 4);
      uint2 wv; wv.x = w0; wv.y = w1;
      *(uint2*)((char*)Pa + byte) = wv;
    }

    f32x4 av;
    #pragma unroll
    for (int j = 0; j < 4; ++j) av[j] = __shfl(alpha, lk * 4 + j, 64);
    #pragma unroll
    for (int ni = 0; ni < 4; ++ni) acc_o[ni] *= av;

    #pragma unroll
    for (int kk = 0; kk < 2; ++kk) {
      bf16x8 ap = ldsw(Pa, lr, kk * 64 + lk * 16);
      #pragma unroll
      for (int ni = 0; ni < 4; ++ni) {
        bf16x8 bv = ldsw(Vs[cur], ni * 16 + lr, kk * 64 + lk * 16);
        acc_o[ni] = __builtin_amdgcn_mfma_f32_16x16x32_bf16(ap, bv, acc_o[ni], 0, 0, 0);
      }
    }
    __syncthreads();
  }

  float il = 1.f / l_;
  f32x4 ilv;
  #pragma unroll
  for (int j = 0; j < 4; ++j) ilv[j] = __shfl(il, lk * 4 + j, 64);
  #pragma unroll
  for (int ni = 0; ni < 4; ++ni)
    #pragma unroll
    for (int j = 0; j < 4; ++j) {
      int qrow = (qt << 6) + wid * 16 + lk * 4 + j;
      int c = h * 64 + ni * 16 + lr;
      out[((size_t)(b * SEQ + qrow)) * CDIM + c] = f32_to_bf16(acc_o[ni][j] * ilv[j]);
    }
}

extern "C" void kernel_launch(void* const* d_in, const int* in_sizes, int n_in,
                              void* d_out, int out_size, void* d_ws, size_t ws_size,
                              hipStream_t stream) {
  const float* x     = (const float*)d_in[0];
  const float* w_qkv = (const float*)d_in[1];
  const float* w_o   = (const float*)d_in[2];
  float* out = (float*)d_out;

  u16* xb    = (u16*)d_ws;
  u16* wqkvT = xb    + (size_t)MTOK * CDIM;
  u16* woT   = wqkvT + (size_t)NQKV * CDIM;
  u16* qb    = woT   + (size_t)CDIM * CDIM;
  u16* kb    = qb    + (size_t)NPAIR * SEQ * HD;
  u16* vb    = kb    + (size_t)NPAIR * SEQ * HD;   // stored transposed: [pair][d][n]
  u16* ao    = vb    + (size_t)NPAIR * SEQ * HD;

  cvt_x_kernel<<<dim3((MTOK * CDIM) / (256 * 8)), 256, 0, stream>>>(x, xb);
  transpose_cvt_kernel<<<dim3((CDIM / 64) * (NQKV / 64)), 256, 0, stream>>>(w_qkv, wqkvT, CDIM, NQKV);
  transpose_cvt_kernel<<<dim3((CDIM / 64) * (CDIM / 64)), 256, 0, stream>>>(w_o, woT, CDIM, CDIM);

  {
    int nwg = (MTOK / 128) * (NQKV / 128);   // 1152, %8==0
    gemm_bt<0><<<dim3(nwg), 256, 0, stream>>>(
        xb, wqkvT, nullptr, qb, kb, vb, MTOK, NQKV, CDIM, nwg / 8);
  }

  attn_kernel<<<dim3(NPAIR * 16), 256, 0, stream>>>(qb, kb, vb, ao);

  {
    int nwg = (MTOK / 128) * (CDIM / 128);   // 384, %8==0
    gemm_bt<1><<<dim3(nwg), 256, 0, stream>>>(
        ao, woT, out, nullptr, nullptr, nullptr, MTOK, CDIM, CDIM, nwg / 8);
  }
}